// Round 2
// baseline (88.156 us; speedup 1.0000x reference)
//
#include <hip/hip_runtime.h>

// MultiGaussSpatialConv: B=1, N=M=8192, D=3, C=16, fp32.
// out[n,c] = sum_i w_i * (sum_m e_i(n,m) yf[m,c]) / (sum_m e_i(n,m))
// e_i = exp(-d2/(2 s^2)), 1/(2 s^2) = {200, 50, 12.5} -> e0 = e2^16, e1 = e2^4.
//
// R21: NT=2 n-tiles per wave. All main-loop loads (fragy, fragf) are
// n-independent; at NT=1 the 4096 waves pulled 400 MB through L1/L2 for
// 768 KB of unique data (L1-return-BW bound, ~10 us > 4.4 us VALU floor).
// Each wave now owns 32 n (two 16-n tiles sharing the same A-frag loads):
// load traffic halves. Grid (64,8) = 512 blocks, 2 waves/SIMD -- body is
// barrier-free pure-ILP register code (R20 removed the LDS transpose via
// group-permuted A-frag rows in prep), so TLP=2 suffices.
//  - prep: y -> split-fp16 rank-13 arg-A-frags (group-permuted rows);
//    yf -> fp16 B-frags (global, L2-resident). (unchanged from R20)
//  - main: arg^T via 16x16x32 f16 MFMA (split-fp16, ~5e-5 err); v_exp_f32;
//    packed fp16 power chain (e2 -> e2^4 -> e2^16, quantization cancels in
//    num/den ratio); e-MFMA with yf as A operand. 12 accs (2 tiles x 3 sig
//    x {num,den}).
//  - reduce: sums 8 partials, finalizes weighted ratio. (unchanged)

static constexpr int Nn = 8192;
static constexpr int Mm = 8192;
static constexpr int NCH = 8;               // m-chunks
static constexpr int MC  = Mm / NCH;        // 1024 m per chunk
static constexpr int NKT = MC / 32;         // kt per wave (32)
static constexpr float KC = 36.0673761f;    // 25 * log2(e)
static constexpr float KD = -18.0336880f;   // -12.5 * log2(e)

typedef _Float16 half8 __attribute__((ext_vector_type(8)));
typedef __fp16  fp16x2 __attribute__((ext_vector_type(2)));
typedef float  float4v __attribute__((ext_vector_type(4)));

#define MFMA_F16 __builtin_amdgcn_mfma_f32_16x16x32_f16
#define EXP2F(v) __builtin_amdgcn_exp2f(v)

// ---------------- prep: y -> split-fp16 arg-A-frags; yf -> fp16 frags
__global__ __launch_bounds__(256) void mgsc_prep(
    const float* __restrict__ y, const float* __restrict__ yf,
    _Float16* __restrict__ fragy, _Float16* __restrict__ fragf)
{
    const int t = blockIdx.x * 256 + threadIdx.x;   // 0 .. Mm*32-1
    const int m = t >> 5, kk = t & 31;
    const float ax = y[3 * m], ay = y[3 * m + 1], az = y[3 * m + 2];
    const float Ycx = KC * ax, Ycy = KC * ay, Ycz = KC * az;
    const _Float16 Yhx = (_Float16)Ycx, Yhy = (_Float16)Ycy, Yhz = (_Float16)Ycz;
    const _Float16 Ylx = (_Float16)(Ycx - (float)Yhx);
    const _Float16 Yly = (_Float16)(Ycy - (float)Yhy);
    const _Float16 Ylz = (_Float16)(Ycz - (float)Yhz);
    const float Wy = KD * __fmaf_rn(ax, ax, __fmaf_rn(ay, ay, az * az));
    const _Float16 Wyh = (_Float16)Wy;
    const _Float16 Wyl = (_Float16)(Wy - (float)Wyh);
    _Float16 v = (_Float16)0.0f;
    switch (kk) {
        case 0: case 6: v = Yhx; break;
        case 1: case 7: v = Yhy; break;
        case 2: case 8: v = Yhz; break;
        case 3: v = Ylx; break;
        case 4: v = Yly; break;
        case 5: v = Ylz; break;
        case 9:  v = Wyh; break;
        case 10: v = Wyl; break;
        case 11: case 12: v = (_Float16)1.0f; break;
        default: break;
    }
    // Group-permuted A-frag placement (R20):
    //   frag pair index = 2*(m>>5) + ((m>>2)&1)
    //   row rho = 4*((m&31)>>3) + (m&3)   (lane-group g = (m&31)>>3)
    //   lane = (kk>>3)*16 + rho, element j = kk&7
    const int fragidx = ((m >> 5) << 1) + ((m >> 2) & 1);
    const int rho = (((m >> 3) & 3) << 2) + (m & 3);
    const int idx = (fragidx << 9) + ((((kk >> 3) << 4) + rho) << 3) + (kk & 7);
    fragy[idx] = v;
    if (t < Mm * 16) {                              // yf frags (same as R13)
        const int m2 = t >> 4, c2 = t & 15;
        const int idx2 = ((m2 >> 5) << 9) + ((((m2 & 31) >> 3) << 4) + c2) * 8 + (m2 & 7);
        fragf[idx2] = (_Float16)yf[t];              // RNE
    }
}

// ---------------- main: grid (64, NCH); 4 waves/block, 32 n per wave (NT=2)
__global__ __launch_bounds__(256, 2) void mgsc_main(
    const float* __restrict__ x, const _Float16* __restrict__ fragy,
    const _Float16* __restrict__ fragf, float* __restrict__ part)
{
    const int tid  = threadIdx.x;
    const int wave = tid >> 6, lane = tid & 63;
    const int g    = lane >> 4, c = lane & 15;      // c = n_local within tile
    const int xb   = blockIdx.x, yb = blockIdx.y;
    const int n0   = (xb * 4 + wave) * 32;          // 32 n per wave
    const int nA   = n0 + c;                        // tile A rows
    const int nB   = n0 + 16 + c;                   // tile B rows

    // ---- build x-side B operands for the arg-MFMA (hoisted, per lane)
    const _Float16 z16 = (_Float16)0.0f, one16 = (_Float16)1.0f;
    half8 B1a, B1b;
#pragma unroll
    for (int tI = 0; tI < 2; ++tI) {
        const int nrow = tI ? nB : nA;
        const float xx = x[3 * nrow], xy = x[3 * nrow + 1], xz = x[3 * nrow + 2];
        const _Float16 xhx = (_Float16)xx, xhy = (_Float16)xy, xhz = (_Float16)xz;
        const _Float16 xlx = (_Float16)(xx - (float)xhx);
        const _Float16 xly = (_Float16)(xy - (float)xhy);
        const _Float16 xlz = (_Float16)(xz - (float)xhz);
        const float Wx = KD * __fmaf_rn(xx, xx, __fmaf_rn(xy, xy, xz * xz));
        const _Float16 Wxh = (_Float16)Wx;
        const _Float16 Wxl = (_Float16)(Wx - (float)Wxh);
        half8 B1;
        if (g == 0)      B1 = half8{xhx, xhy, xhz, xhx, xhy, xhz, xlx, xly};
        else if (g == 1) B1 = half8{xlz, one16, one16, Wxh, Wxl, z16, z16, z16};
        else             B1 = half8{z16, z16, z16, z16, z16, z16, z16, z16};
        if (tI) B1b = B1; else B1a = B1;
    }

    float4v accA0 = {0.f, 0.f, 0.f, 0.f};
    float4v accA1 = accA0, accA2 = accA0, dacA0 = accA0, dacA1 = accA0, dacA2 = accA0;
    float4v accB0 = accA0, accB1 = accA0, accB2 = accA0;
    float4v dacB0 = accA0, dacB1 = accA0, dacB2 = accA0;
    const float4v z4 = accA0;

    const _Float16 bv = (c == 0) ? one16 : z16;     // A-ones row 0 -> dens
    half8 boneA = {bv, bv, bv, bv, bv, bv, bv, bv};

    const size_t ybase = (size_t)(yb * (MC / 16)) << 9;  // 16-m blocks per chunk
    const size_t fbase = (size_t)(yb * NKT) << 9;

    for (int ktl = 0; ktl < NKT; ++ktl) {
        // n-independent stream, shared by both n-tiles
        const half8 A1a = *reinterpret_cast<const half8*>(fragy + ybase + ((size_t)(2 * ktl) << 9) + (lane << 3));
        const half8 A1b = *reinterpret_cast<const half8*>(fragy + ybase + ((size_t)(2 * ktl + 1) << 9) + (lane << 3));
        const half8 Af  = *reinterpret_cast<const half8*>(fragf + fbase + ((size_t)ktl << 9) + (lane << 3));

        // arg^T with group-permuted rows: lane (g,c) gets
        //   D1[r] = arg(m = 32*ktl + 8g + r,     n)
        //   D2[r] = arg(m = 32*ktl + 8g + 4 + r, n)
        const float4v D1a = MFMA_F16(A1a, B1a, z4, 0, 0, 0);
        const float4v D2a = MFMA_F16(A1b, B1a, z4, 0, 0, 0);
        const float4v D1b = MFMA_F16(A1a, B1b, z4, 0, 0, 0);
        const float4v D2b = MFMA_F16(A1b, B1b, z4, 0, 0, 0);

        // exp + pack straight into the e-MFMA B-frag (k = 8g+j, col = n)
        union { fp16x2 h2[4]; half8 v; } E2a, E1a, E0a, E2b, E1b, E0b;
        E2a.h2[0] = __builtin_amdgcn_cvt_pkrtz(EXP2F(D1a[0]), EXP2F(D1a[1]));
        E2a.h2[1] = __builtin_amdgcn_cvt_pkrtz(EXP2F(D1a[2]), EXP2F(D1a[3]));
        E2a.h2[2] = __builtin_amdgcn_cvt_pkrtz(EXP2F(D2a[0]), EXP2F(D2a[1]));
        E2a.h2[3] = __builtin_amdgcn_cvt_pkrtz(EXP2F(D2a[2]), EXP2F(D2a[3]));
        E2b.h2[0] = __builtin_amdgcn_cvt_pkrtz(EXP2F(D1b[0]), EXP2F(D1b[1]));
        E2b.h2[1] = __builtin_amdgcn_cvt_pkrtz(EXP2F(D1b[2]), EXP2F(D1b[3]));
        E2b.h2[2] = __builtin_amdgcn_cvt_pkrtz(EXP2F(D2b[0]), EXP2F(D2b[1]));
        E2b.h2[3] = __builtin_amdgcn_cvt_pkrtz(EXP2F(D2b[2]), EXP2F(D2b[3]));
#pragma unroll
        for (int jj = 0; jj < 4; ++jj) {
            const fp16x2 s2a = E2a.h2[jj] * E2a.h2[jj];  // v_pk_mul_f16
            E1a.h2[jj] = s2a * s2a;                       // e2^4  (sigma 0.1)
            const fp16x2 s1a = E1a.h2[jj] * E1a.h2[jj];
            E0a.h2[jj] = s1a * s1a;                       // e2^16 (sigma 0.05)
            const fp16x2 s2b = E2b.h2[jj] * E2b.h2[jj];
            E1b.h2[jj] = s2b * s2b;
            const fp16x2 s1b = E1b.h2[jj] * E1b.h2[jj];
            E0b.h2[jj] = s1b * s1b;
        }
        // e-MFMA: A = yf^T (row=c, k=m), B = e^T (k=m, col=n)
        accA0 = MFMA_F16(Af, E0a.v, accA0, 0, 0, 0);
        accA1 = MFMA_F16(Af, E1a.v, accA1, 0, 0, 0);
        accA2 = MFMA_F16(Af, E2a.v, accA2, 0, 0, 0);
        dacA0 = MFMA_F16(boneA, E0a.v, dacA0, 0, 0, 0);
        dacA1 = MFMA_F16(boneA, E1a.v, dacA1, 0, 0, 0);
        dacA2 = MFMA_F16(boneA, E2a.v, dacA2, 0, 0, 0);
        accB0 = MFMA_F16(Af, E0b.v, accB0, 0, 0, 0);
        accB1 = MFMA_F16(Af, E1b.v, accB1, 0, 0, 0);
        accB2 = MFMA_F16(Af, E2b.v, accB2, 0, 0, 0);
        dacB0 = MFMA_F16(boneA, E0b.v, dacB0, 0, 0, 0);
        dacB1 = MFMA_F16(boneA, E1b.v, dacB1, 0, 0, 0);
        dacB2 = MFMA_F16(boneA, E2b.v, dacB2, 0, 0, 0);
    }

    // ---- epilogue: D col = n = c(lane), rows = channel 4g + r
    float* rowA = part + ((size_t)yb * Nn + nA) * 52;
    float* rowB = part + ((size_t)yb * Nn + nB) * 52;
#pragma unroll
    for (int r = 0; r < 4; ++r) {
        const int ch = 4 * g + r;
        rowA[ch]      = accA0[r];
        rowA[16 + ch] = accA1[r];
        rowA[32 + ch] = accA2[r];
        rowB[ch]      = accB0[r];
        rowB[16 + ch] = accB1[r];
        rowB[32 + ch] = accB2[r];
    }
    if (g == 0) {                                   // dens live in row 0
        rowA[48] = dacA0[0];
        rowA[49] = dacA1[0];
        rowA[50] = dacA2[0];
        rowB[48] = dacB0[0];
        rowB[49] = dacB1[0];
        rowB[50] = dacB2[0];
    }
}

// ---------------- reduce: thread (n,c) sums NCH chunks, finalizes
__global__ __launch_bounds__(256) void mgsc_reduce(
    const float* __restrict__ part, float* __restrict__ out)
{
    const int t = blockIdx.x * 256 + threadIdx.x;   // 0 .. Nn*16-1
    const int n = t >> 4, c = t & 15;
    float s0 = 0.f, s1 = 0.f, s2 = 0.f, d0 = 0.f, d1 = 0.f, d2 = 0.f;
#pragma unroll
    for (int k = 0; k < NCH; ++k) {
        const float* row = part + ((size_t)k * Nn + n) * 52;
        s0 += row[c];
        s1 += row[16 + c];
        s2 += row[32 + c];
        d0 += row[48];
        d1 += row[49];
        d2 += row[50];
    }
    out[(size_t)n * 16 + c] = 0.3f * s0 / d0 + 0.3f * s1 / d1 + 0.4f * s2 / d2;
}

// ---------------- fused VALU fallback (workspace too small)
__global__ __launch_bounds__(256) void mgsc_fused(
    const float* __restrict__ x, const float* __restrict__ y,
    const float* __restrict__ yf, float* __restrict__ out)
{
    __shared__ float yS[256 * 3];
    __shared__ float yfS[256 * 16];
    const int tid = threadIdx.x;
    const int n   = blockIdx.x * 256 + tid;
    const float xx = x[3 * n], xy = x[3 * n + 1], xz = x[3 * n + 2];
    float a0[16], a1[16], a2[16];
#pragma unroll
    for (int c = 0; c < 16; ++c) { a0[c] = 0.f; a1[c] = 0.f; a2[c] = 0.f; }
    float den0 = 0.f, den1 = 0.f, den2 = 0.f;
    for (int mt = 0; mt < Mm; mt += 256) {
        const float4* ysrc = reinterpret_cast<const float4*>(y + (size_t)mt * 3);
        if (tid < 192) reinterpret_cast<float4*>(yS)[tid] = ysrc[tid];
        const float4* fsrc = reinterpret_cast<const float4*>(yf + (size_t)mt * 16);
#pragma unroll
        for (int k = 0; k < 4; ++k)
            reinterpret_cast<float4*>(yfS)[tid + 256 * k] = fsrc[tid + 256 * k];
        __syncthreads();
        for (int mm = 0; mm < 256; ++mm) {
            const float dx = xx - yS[3 * mm], dy = xy - yS[3 * mm + 1], dz = xz - yS[3 * mm + 2];
            const float d2 = dx * dx + dy * dy + dz * dz;
            const float e2 = __expf(-12.5f * d2);
            const float t = e2 * e2, e1 = t * t, u = e1 * e1, e0 = u * u;
            den0 += e0; den1 += e1; den2 += e2;
            const float4* fr = reinterpret_cast<const float4*>(yfS + mm * 16);
#pragma unroll
            for (int k = 0; k < 4; ++k) {
                const float4 f = fr[k];
                a0[4*k+0] += e0 * f.x; a0[4*k+1] += e0 * f.y; a0[4*k+2] += e0 * f.z; a0[4*k+3] += e0 * f.w;
                a1[4*k+0] += e1 * f.x; a1[4*k+1] += e1 * f.y; a1[4*k+2] += e1 * f.z; a1[4*k+3] += e1 * f.w;
                a2[4*k+0] += e2 * f.x; a2[4*k+1] += e2 * f.y; a2[4*k+2] += e2 * f.z; a2[4*k+3] += e2 * f.w;
            }
        }
        __syncthreads();
    }
    const float r0 = 0.3f / den0, r1 = 0.3f / den1, r2 = 0.4f / den2;
#pragma unroll
    for (int c = 0; c < 16; ++c)
        out[(size_t)n * 16 + c] = a0[c] * r0 + a1[c] * r1 + a2[c] * r2;
}

extern "C" void kernel_launch(void* const* d_in, const int* in_sizes, int n_in,
                              void* d_out, int out_size, void* d_ws, size_t ws_size,
                              hipStream_t stream) {
    const float* x  = (const float*)d_in[0];
    const float* y  = (const float*)d_in[1];
    const float* yf = (const float*)d_in[2];
    float* out = (float*)d_out;

    const size_t fragyB = (size_t)(Mm / 16) * 512 * sizeof(_Float16); // 512 KB
    const size_t fragfB = (size_t)Mm * 16 * sizeof(_Float16);         // 256 KB
    const size_t partB  = (size_t)NCH * Nn * 52 * sizeof(float);      // 13.6 MB
    if (fragyB + fragfB + partB > ws_size) {
        mgsc_fused<<<Nn / 256, 256, 0, stream>>>(x, y, yf, out);
        return;
    }
    _Float16* fragy = (_Float16*)d_ws;
    _Float16* fragf = (_Float16*)((char*)d_ws + fragyB);
    float*    part  = (float*)((char*)d_ws + fragyB + fragfB);

    mgsc_prep<<<(Mm * 32) / 256, 256, 0, stream>>>(y, yf, fragy, fragf);
    mgsc_main<<<dim3(Nn / 128, NCH), 256, 0, stream>>>(x, fragy, fragf, part);
    mgsc_reduce<<<(Nn * 16) / 256, 256, 0, stream>>>(part, out);
}

// Round 5
// 85.565 us; speedup vs baseline: 1.0303x; 1.0303x over previous
//
#include <hip/hip_runtime.h>

// MultiGaussSpatialConv: B=1, N=M=8192, D=3, C=16, fp32.
// out[n,c] = sum_i w_i * (sum_m e_i(n,m) yf[m,c]) / (sum_m e_i(n,m))
// e_i = exp(-d2/(2 s^2)), 1/(2 s^2) = {200, 50, 12.5} -> e0 = e2^16, e1 = e2^4.
//
// R24 = resubmission of R23 (infra failure last round, never measured).
// R23 = exact restore of R20 (best verified: 85.8 us, absmax 1.953e-3) plus
// dwordx4 epilogue stores. R22's cooperative fusion failed: coop launch does
// not execute under the harness's graph capture (out stayed poison-zero).
// Session accounting: 3 structural rounds moved dur_us <= +-2.5%; the timed
// window is dominated by harness ws-poison fills (43 us @ 78% HBM peak,
// un-addressable); our kernels sum to ~15-20 us.
//  - prep: y -> split-fp16 rank-13 arg-A-frags (group-permuted rows so the
//    arg-MFMA D layout feeds the e-MFMA B operand directly, no LDS);
//    yf -> fp16 B-frags (global, L2-resident).
//  - main: arg^T via one 16x16x32 f16 MFMA per 16 m (split-fp16, ~5e-5 err);
//    v_exp_f32; packed fp16 power chain (e2 -> e2^4 -> e2^16, quantization
//    cancels in num/den ratio); e-MFMA with yf as A operand. Grid (128,8),
//    4 waves/block, barrier-free register-only loop.
//  - reduce: sums 8 partials, finalizes weighted ratio.

static constexpr int Nn = 8192;
static constexpr int Mm = 8192;
static constexpr int NCH = 8;               // m-chunks
static constexpr int MC  = Mm / NCH;        // 1024 m per chunk
static constexpr int NKT = MC / 32;         // kt per wave (32)
static constexpr float KC = 36.0673761f;    // 25 * log2(e)
static constexpr float KD = -18.0336880f;   // -12.5 * log2(e)

typedef _Float16 half8 __attribute__((ext_vector_type(8)));
typedef __fp16  fp16x2 __attribute__((ext_vector_type(2)));
typedef float  float4v __attribute__((ext_vector_type(4)));

#define MFMA_F16 __builtin_amdgcn_mfma_f32_16x16x32_f16
#define EXP2F(v) __builtin_amdgcn_exp2f(v)

// ---------------- prep: y -> split-fp16 arg-A-frags; yf -> fp16 frags
__global__ __launch_bounds__(256) void mgsc_prep(
    const float* __restrict__ y, const float* __restrict__ yf,
    _Float16* __restrict__ fragy, _Float16* __restrict__ fragf)
{
    const int t = blockIdx.x * 256 + threadIdx.x;   // 0 .. Mm*32-1
    const int m = t >> 5, kk = t & 31;
    const float ax = y[3 * m], ay = y[3 * m + 1], az = y[3 * m + 2];
    const float Ycx = KC * ax, Ycy = KC * ay, Ycz = KC * az;
    const _Float16 Yhx = (_Float16)Ycx, Yhy = (_Float16)Ycy, Yhz = (_Float16)Ycz;
    const _Float16 Ylx = (_Float16)(Ycx - (float)Yhx);
    const _Float16 Yly = (_Float16)(Ycy - (float)Yhy);
    const _Float16 Ylz = (_Float16)(Ycz - (float)Yhz);
    const float Wy = KD * __fmaf_rn(ax, ax, __fmaf_rn(ay, ay, az * az));
    const _Float16 Wyh = (_Float16)Wy;
    const _Float16 Wyl = (_Float16)(Wy - (float)Wyh);
    _Float16 v = (_Float16)0.0f;
    switch (kk) {
        case 0: case 6: v = Yhx; break;
        case 1: case 7: v = Yhy; break;
        case 2: case 8: v = Yhz; break;
        case 3: v = Ylx; break;
        case 4: v = Yly; break;
        case 5: v = Ylz; break;
        case 9:  v = Wyh; break;
        case 10: v = Wyl; break;
        case 11: case 12: v = (_Float16)1.0f; break;
        default: break;
    }
    // Group-permuted A-frag placement (R20):
    //   frag pair index = 2*(m>>5) + ((m>>2)&1)
    //   row rho = 4*((m&31)>>3) + (m&3)   (lane-group g = (m&31)>>3)
    //   lane = (kk>>3)*16 + rho, element j = kk&7
    const int fragidx = ((m >> 5) << 1) + ((m >> 2) & 1);
    const int rho = (((m >> 3) & 3) << 2) + (m & 3);
    const int idx = (fragidx << 9) + ((((kk >> 3) << 4) + rho) << 3) + (kk & 7);
    fragy[idx] = v;
    if (t < Mm * 16) {                              // yf frags (same as R13)
        const int m2 = t >> 4, c2 = t & 15;
        const int idx2 = ((m2 >> 5) << 9) + ((((m2 & 31) >> 3) << 4) + c2) * 8 + (m2 & 7);
        fragf[idx2] = (_Float16)yf[t];              // RNE
    }
}

// ---------------- main: grid (128, NCH); 4 waves/block, one n-tile per wave
__global__ __launch_bounds__(256, 4) void mgsc_main(
    const float* __restrict__ x, const _Float16* __restrict__ fragy,
    const _Float16* __restrict__ fragf, float* __restrict__ part)
{
    const int tid  = threadIdx.x;
    const int wave = tid >> 6, lane = tid & 63;
    const int g    = lane >> 4, c = lane & 15;      // c = n_local
    const int xb   = blockIdx.x, yb = blockIdx.y;
    const int n0   = (xb * 4 + wave) * 16;
    const int nrow = n0 + c;

    // ---- build x-side B operand for the arg-MFMA (hoisted, per lane)
    const float xx = x[3 * nrow], xy = x[3 * nrow + 1], xz = x[3 * nrow + 2];
    const _Float16 xhx = (_Float16)xx, xhy = (_Float16)xy, xhz = (_Float16)xz;
    const _Float16 xlx = (_Float16)(xx - (float)xhx);
    const _Float16 xly = (_Float16)(xy - (float)xhy);
    const _Float16 xlz = (_Float16)(xz - (float)xhz);
    const float Wx = KD * __fmaf_rn(xx, xx, __fmaf_rn(xy, xy, xz * xz));
    const _Float16 Wxh = (_Float16)Wx;
    const _Float16 Wxl = (_Float16)(Wx - (float)Wxh);
    const _Float16 z16 = (_Float16)0.0f, one16 = (_Float16)1.0f;
    half8 B1;
    if (g == 0)      B1 = half8{xhx, xhy, xhz, xhx, xhy, xhz, xlx, xly};
    else if (g == 1) B1 = half8{xlz, one16, one16, Wxh, Wxl, z16, z16, z16};
    else             B1 = half8{z16, z16, z16, z16, z16, z16, z16, z16};

    float4v acc0 = {0.f, 0.f, 0.f, 0.f}, acc1 = acc0, acc2 = acc0;
    float4v dac0 = acc0, dac1 = acc0, dac2 = acc0;
    const float4v z4 = acc0;

    const _Float16 bv = (c == 0) ? one16 : z16;     // A-ones row 0 -> dens
    half8 boneA = {bv, bv, bv, bv, bv, bv, bv, bv};

    const size_t ybase = (size_t)(yb * (MC / 16)) << 9;  // 16-m blocks per chunk
    const size_t fbase = (size_t)(yb * NKT) << 9;

    for (int ktl = 0; ktl < NKT; ++ktl) {
        const half8 A1a = *reinterpret_cast<const half8*>(fragy + ybase + ((size_t)(2 * ktl) << 9) + (lane << 3));
        const half8 A1b = *reinterpret_cast<const half8*>(fragy + ybase + ((size_t)(2 * ktl + 1) << 9) + (lane << 3));
        const half8 Af  = *reinterpret_cast<const half8*>(fragf + fbase + ((size_t)ktl << 9) + (lane << 3));

        // arg^T with group-permuted rows: lane (g,c) gets
        //   D1[r] = arg(m = 32*ktl + 8g + r,     n = n0 + c)
        //   D2[r] = arg(m = 32*ktl + 8g + 4 + r, n = n0 + c)
        const float4v D1 = MFMA_F16(A1a, B1, z4, 0, 0, 0);
        const float4v D2 = MFMA_F16(A1b, B1, z4, 0, 0, 0);

        // exp + pack straight into the e-MFMA B-frag (k = 8g+j, col = n)
        union { fp16x2 h2[4]; half8 v; } E2p, E1p, E0p;
        E2p.h2[0] = __builtin_amdgcn_cvt_pkrtz(EXP2F(D1[0]), EXP2F(D1[1]));
        E2p.h2[1] = __builtin_amdgcn_cvt_pkrtz(EXP2F(D1[2]), EXP2F(D1[3]));
        E2p.h2[2] = __builtin_amdgcn_cvt_pkrtz(EXP2F(D2[0]), EXP2F(D2[1]));
        E2p.h2[3] = __builtin_amdgcn_cvt_pkrtz(EXP2F(D2[2]), EXP2F(D2[3]));
#pragma unroll
        for (int jj = 0; jj < 4; ++jj) {
            const fp16x2 s2 = E2p.h2[jj] * E2p.h2[jj];  // v_pk_mul_f16
            E1p.h2[jj] = s2 * s2;                        // e2^4  (sigma 0.1)
            const fp16x2 s1 = E1p.h2[jj] * E1p.h2[jj];
            E0p.h2[jj] = s1 * s1;                        // e2^16 (sigma 0.05)
        }
        // e-MFMA: A = yf^T (row=c, k=m), B = e^T (k=m, col=n)
        acc0 = MFMA_F16(Af, E0p.v, acc0, 0, 0, 0);
        acc1 = MFMA_F16(Af, E1p.v, acc1, 0, 0, 0);
        acc2 = MFMA_F16(Af, E2p.v, acc2, 0, 0, 0);
        dac0 = MFMA_F16(boneA, E0p.v, dac0, 0, 0, 0);
        dac1 = MFMA_F16(boneA, E1p.v, dac1, 0, 0, 0);
        dac2 = MFMA_F16(boneA, E2p.v, dac2, 0, 0, 0);
    }

    // ---- epilogue: D col = n = c(lane), rows = channel 4g + r
    // row stride 52 floats = 208 B = 13*16 B -> all three stores 16 B aligned
    float* row = part + ((size_t)yb * Nn + (n0 + c)) * 52;
    *reinterpret_cast<float4v*>(row + 4 * g)      = acc0;
    *reinterpret_cast<float4v*>(row + 16 + 4 * g) = acc1;
    *reinterpret_cast<float4v*>(row + 32 + 4 * g) = acc2;
    if (g == 0) {                                   // dens live in row 0
        row[48] = dac0[0];
        row[49] = dac1[0];
        row[50] = dac2[0];
    }
}

// ---------------- reduce: thread (n,c) sums NCH chunks, finalizes
__global__ __launch_bounds__(256) void mgsc_reduce(
    const float* __restrict__ part, float* __restrict__ out)
{
    const int t = blockIdx.x * 256 + threadIdx.x;   // 0 .. Nn*16-1
    const int n = t >> 4, c = t & 15;
    float s0 = 0.f, s1 = 0.f, s2 = 0.f, d0 = 0.f, d1 = 0.f, d2 = 0.f;
#pragma unroll
    for (int k = 0; k < NCH; ++k) {
        const float* row = part + ((size_t)k * Nn + n) * 52;
        s0 += row[c];
        s1 += row[16 + c];
        s2 += row[32 + c];
        d0 += row[48];
        d1 += row[49];
        d2 += row[50];
    }
    out[(size_t)n * 16 + c] = 0.3f * s0 / d0 + 0.3f * s1 / d1 + 0.4f * s2 / d2;
}

// ---------------- fused VALU fallback (workspace too small)
__global__ __launch_bounds__(256) void mgsc_fused(
    const float* __restrict__ x, const float* __restrict__ y,
    const float* __restrict__ yf, float* __restrict__ out)
{
    __shared__ float yS[256 * 3];
    __shared__ float yfS[256 * 16];
    const int tid = threadIdx.x;
    const int n   = blockIdx.x * 256 + tid;
    const float xx = x[3 * n], xy = x[3 * n + 1], xz = x[3 * n + 2];
    float a0[16], a1[16], a2[16];
#pragma unroll
    for (int c = 0; c < 16; ++c) { a0[c] = 0.f; a1[c] = 0.f; a2[c] = 0.f; }
    float den0 = 0.f, den1 = 0.f, den2 = 0.f;
    for (int mt = 0; mt < Mm; mt += 256) {
        const float4* ysrc = reinterpret_cast<const float4*>(y + (size_t)mt * 3);
        if (tid < 192) reinterpret_cast<float4*>(yS)[tid] = ysrc[tid];
        const float4* fsrc = reinterpret_cast<const float4*>(yf + (size_t)mt * 16);
#pragma unroll
        for (int k = 0; k < 4; ++k)
            reinterpret_cast<float4*>(yfS)[tid + 256 * k] = fsrc[tid + 256 * k];
        __syncthreads();
        for (int mm = 0; mm < 256; ++mm) {
            const float dx = xx - yS[3 * mm], dy = xy - yS[3 * mm + 1], dz = xz - yS[3 * mm + 2];
            const float d2 = dx * dx + dy * dy + dz * dz;
            const float e2 = __expf(-12.5f * d2);
            const float t = e2 * e2, e1 = t * t, u = e1 * e1, e0 = u * u;
            den0 += e0; den1 += e1; den2 += e2;
            const float4* fr = reinterpret_cast<const float4*>(yfS + mm * 16);
#pragma unroll
            for (int k = 0; k < 4; ++k) {
                const float4 f = fr[k];
                a0[4*k+0] += e0 * f.x; a0[4*k+1] += e0 * f.y; a0[4*k+2] += e0 * f.z; a0[4*k+3] += e0 * f.w;
                a1[4*k+0] += e1 * f.x; a1[4*k+1] += e1 * f.y; a1[4*k+2] += e1 * f.z; a1[4*k+3] += e1 * f.w;
                a2[4*k+0] += e2 * f.x; a2[4*k+1] += e2 * f.y; a2[4*k+2] += e2 * f.z; a2[4*k+3] += e2 * f.w;
            }
        }
        __syncthreads();
    }
    const float r0 = 0.3f / den0, r1 = 0.3f / den1, r2 = 0.4f / den2;
#pragma unroll
    for (int c = 0; c < 16; ++c)
        out[(size_t)n * 16 + c] = a0[c] * r0 + a1[c] * r1 + a2[c] * r2;
}

extern "C" void kernel_launch(void* const* d_in, const int* in_sizes, int n_in,
                              void* d_out, int out_size, void* d_ws, size_t ws_size,
                              hipStream_t stream) {
    const float* x  = (const float*)d_in[0];
    const float* y  = (const float*)d_in[1];
    const float* yf = (const float*)d_in[2];
    float* out = (float*)d_out;

    const size_t fragyB = (size_t)(Mm / 16) * 512 * sizeof(_Float16); // 512 KB
    const size_t fragfB = (size_t)Mm * 16 * sizeof(_Float16);         // 256 KB
    const size_t partB  = (size_t)NCH * Nn * 52 * sizeof(float);      // 13.6 MB
    if (fragyB + fragfB + partB > ws_size) {
        mgsc_fused<<<Nn / 256, 256, 0, stream>>>(x, y, yf, out);
        return;
    }
    _Float16* fragy = (_Float16*)d_ws;
    _Float16* fragf = (_Float16*)((char*)d_ws + fragyB);
    float*    part  = (float*)((char*)d_ws + fragyB + fragfB);

    mgsc_prep<<<(Mm * 32) / 256, 256, 0, stream>>>(y, yf, fragy, fragf);
    mgsc_main<<<dim3(Nn / 64, NCH), 256, 0, stream>>>(x, fragy, fragf, part);
    mgsc_reduce<<<(Nn * 16) / 256, 256, 0, stream>>>(part, out);
}

// Round 6
// 82.110 us; speedup vs baseline: 1.0736x; 1.0421x over previous
//
#include <hip/hip_runtime.h>

// MultiGaussSpatialConv: B=1, N=M=8192, D=3, C=16, fp32.
// out[n,c] = sum_i w_i * (sum_m e_i(n,m) yf[m,c]) / (sum_m e_i(n,m))
// e_i = exp(-d2/(2 s^2)), 1/(2 s^2) = {200, 50, 12.5} -> e0 = e2^16, e1 = e2^4.
//
// R25: fuse reduce into main via block-local LDS reduction. One 512-thread
// block owns one 16-n tile; its 8 waves each process one 1024-m chunk with
// the EXACT verified R20/R24 per-wave body (85.6 us, absmax 1.953e-3).
// Epilogue: waves write partials to LDS (28 KB), __syncthreads, 256 threads
// sum 8 chunks and finalize. Deletes: part buffer (13.6 MB HBM write +
// 13.9 MB strided read), the reduce dispatch, one launch gap. No cross-block
// coherence anywhere (all 8 chunks of a tile are in-block).
//  - prep: y -> split-fp16 rank-13 arg-A-frags (group-permuted rows so the
//    arg-MFMA D layout feeds the e-MFMA B operand directly, no LDS in loop);
//    yf -> fp16 B-frags (global, L2-resident). (unchanged)
//  - main: grid 512 x 512 thr (2 blocks/CU, 16 waves/CU, VGPR cap 128 --
//    same occupancy as R24). Per wave: arg^T via 16x16x32 f16 MFMA
//    (split-fp16), v_exp_f32, packed fp16 power chain, e-MFMA with yf as A.
//    Barrier-free register-only loop; single syncthreads at epilogue.

static constexpr int Nn = 8192;
static constexpr int Mm = 8192;
static constexpr int NCH = 8;               // m-chunks = waves per block
static constexpr int MC  = Mm / NCH;        // 1024 m per chunk
static constexpr int NKT = MC / 32;         // kt per wave (32)
static constexpr float KC = 36.0673761f;    // 25 * log2(e)
static constexpr float KD = -18.0336880f;   // -12.5 * log2(e)

typedef _Float16 half8 __attribute__((ext_vector_type(8)));
typedef __fp16  fp16x2 __attribute__((ext_vector_type(2)));
typedef float  float4v __attribute__((ext_vector_type(4)));

#define MFMA_F16 __builtin_amdgcn_mfma_f32_16x16x32_f16
#define EXP2F(v) __builtin_amdgcn_exp2f(v)

// ---------------- prep: y -> split-fp16 arg-A-frags; yf -> fp16 frags
__global__ __launch_bounds__(256) void mgsc_prep(
    const float* __restrict__ y, const float* __restrict__ yf,
    _Float16* __restrict__ fragy, _Float16* __restrict__ fragf)
{
    const int t = blockIdx.x * 256 + threadIdx.x;   // 0 .. Mm*32-1
    const int m = t >> 5, kk = t & 31;
    const float ax = y[3 * m], ay = y[3 * m + 1], az = y[3 * m + 2];
    const float Ycx = KC * ax, Ycy = KC * ay, Ycz = KC * az;
    const _Float16 Yhx = (_Float16)Ycx, Yhy = (_Float16)Ycy, Yhz = (_Float16)Ycz;
    const _Float16 Ylx = (_Float16)(Ycx - (float)Yhx);
    const _Float16 Yly = (_Float16)(Ycy - (float)Yhy);
    const _Float16 Ylz = (_Float16)(Ycz - (float)Yhz);
    const float Wy = KD * __fmaf_rn(ax, ax, __fmaf_rn(ay, ay, az * az));
    const _Float16 Wyh = (_Float16)Wy;
    const _Float16 Wyl = (_Float16)(Wy - (float)Wyh);
    _Float16 v = (_Float16)0.0f;
    switch (kk) {
        case 0: case 6: v = Yhx; break;
        case 1: case 7: v = Yhy; break;
        case 2: case 8: v = Yhz; break;
        case 3: v = Ylx; break;
        case 4: v = Yly; break;
        case 5: v = Ylz; break;
        case 9:  v = Wyh; break;
        case 10: v = Wyl; break;
        case 11: case 12: v = (_Float16)1.0f; break;
        default: break;
    }
    // Group-permuted A-frag placement (R20):
    //   frag pair index = 2*(m>>5) + ((m>>2)&1)
    //   row rho = 4*((m&31)>>3) + (m&3)   (lane-group g = (m&31)>>3)
    //   lane = (kk>>3)*16 + rho, element j = kk&7
    const int fragidx = ((m >> 5) << 1) + ((m >> 2) & 1);
    const int rho = (((m >> 3) & 3) << 2) + (m & 3);
    const int idx = (fragidx << 9) + ((((kk >> 3) << 4) + rho) << 3) + (kk & 7);
    fragy[idx] = v;
    if (t < Mm * 16) {                              // yf frags (same as R13)
        const int m2 = t >> 4, c2 = t & 15;
        const int idx2 = ((m2 >> 5) << 9) + ((((m2 & 31) >> 3) << 4) + c2) * 8 + (m2 & 7);
        fragf[idx2] = (_Float16)yf[t];              // RNE
    }
}

// ---------------- main: grid 512 x 512 thr; wave w = chunk w; one 16-n tile/block
__global__ __launch_bounds__(512, 4) void mgsc_main(
    const float* __restrict__ x, const _Float16* __restrict__ fragy,
    const _Float16* __restrict__ fragf, float* __restrict__ out)
{
    __shared__ float ldsN[NCH][16][52];             // [wave][n_loc][ch 0..47], 52 pad
    __shared__ float ldsD[NCH][16][3];              // dens

    const int tid  = threadIdx.x;
    const int w    = tid >> 6, lane = tid & 63;     // w = wave = m-chunk id
    const int g    = lane >> 4, c = lane & 15;      // c = n_local
    const int n0   = blockIdx.x * 16;
    const int nrow = n0 + c;

    // ---- build x-side B operand for the arg-MFMA (hoisted, per lane)
    const float xx = x[3 * nrow], xy = x[3 * nrow + 1], xz = x[3 * nrow + 2];
    const _Float16 xhx = (_Float16)xx, xhy = (_Float16)xy, xhz = (_Float16)xz;
    const _Float16 xlx = (_Float16)(xx - (float)xhx);
    const _Float16 xly = (_Float16)(xy - (float)xhy);
    const _Float16 xlz = (_Float16)(xz - (float)xhz);
    const float Wx = KD * __fmaf_rn(xx, xx, __fmaf_rn(xy, xy, xz * xz));
    const _Float16 Wxh = (_Float16)Wx;
    const _Float16 Wxl = (_Float16)(Wx - (float)Wxh);
    const _Float16 z16 = (_Float16)0.0f, one16 = (_Float16)1.0f;
    half8 B1;
    if (g == 0)      B1 = half8{xhx, xhy, xhz, xhx, xhy, xhz, xlx, xly};
    else if (g == 1) B1 = half8{xlz, one16, one16, Wxh, Wxl, z16, z16, z16};
    else             B1 = half8{z16, z16, z16, z16, z16, z16, z16, z16};

    float4v acc0 = {0.f, 0.f, 0.f, 0.f}, acc1 = acc0, acc2 = acc0;
    float4v dac0 = acc0, dac1 = acc0, dac2 = acc0;
    const float4v z4 = acc0;

    const _Float16 bv = (c == 0) ? one16 : z16;     // A-ones row 0 -> dens
    half8 boneA = {bv, bv, bv, bv, bv, bv, bv, bv};

    const size_t ybase = (size_t)(w * (MC / 16)) << 9;   // chunk = wave id
    const size_t fbase = (size_t)(w * NKT) << 9;

    for (int ktl = 0; ktl < NKT; ++ktl) {
        const half8 A1a = *reinterpret_cast<const half8*>(fragy + ybase + ((size_t)(2 * ktl) << 9) + (lane << 3));
        const half8 A1b = *reinterpret_cast<const half8*>(fragy + ybase + ((size_t)(2 * ktl + 1) << 9) + (lane << 3));
        const half8 Af  = *reinterpret_cast<const half8*>(fragf + fbase + ((size_t)ktl << 9) + (lane << 3));

        // arg^T with group-permuted rows: lane (g,c) gets
        //   D1[r] = arg(m = chunk_base + 32*ktl + 8g + r,     n = n0 + c)
        //   D2[r] = arg(m = chunk_base + 32*ktl + 8g + 4 + r, n = n0 + c)
        const float4v D1 = MFMA_F16(A1a, B1, z4, 0, 0, 0);
        const float4v D2 = MFMA_F16(A1b, B1, z4, 0, 0, 0);

        // exp + pack straight into the e-MFMA B-frag (k = 8g+j, col = n)
        union { fp16x2 h2[4]; half8 v; } E2p, E1p, E0p;
        E2p.h2[0] = __builtin_amdgcn_cvt_pkrtz(EXP2F(D1[0]), EXP2F(D1[1]));
        E2p.h2[1] = __builtin_amdgcn_cvt_pkrtz(EXP2F(D1[2]), EXP2F(D1[3]));
        E2p.h2[2] = __builtin_amdgcn_cvt_pkrtz(EXP2F(D2[0]), EXP2F(D2[1]));
        E2p.h2[3] = __builtin_amdgcn_cvt_pkrtz(EXP2F(D2[2]), EXP2F(D2[3]));
#pragma unroll
        for (int jj = 0; jj < 4; ++jj) {
            const fp16x2 s2 = E2p.h2[jj] * E2p.h2[jj];  // v_pk_mul_f16
            E1p.h2[jj] = s2 * s2;                        // e2^4  (sigma 0.1)
            const fp16x2 s1 = E1p.h2[jj] * E1p.h2[jj];
            E0p.h2[jj] = s1 * s1;                        // e2^16 (sigma 0.05)
        }
        // e-MFMA: A = yf^T (row=c, k=m), B = e^T (k=m, col=n)
        acc0 = MFMA_F16(Af, E0p.v, acc0, 0, 0, 0);
        acc1 = MFMA_F16(Af, E1p.v, acc1, 0, 0, 0);
        acc2 = MFMA_F16(Af, E2p.v, acc2, 0, 0, 0);
        dac0 = MFMA_F16(boneA, E0p.v, dac0, 0, 0, 0);
        dac1 = MFMA_F16(boneA, E1p.v, dac1, 0, 0, 0);
        dac2 = MFMA_F16(boneA, E2p.v, dac2, 0, 0, 0);
    }

    // ---- epilogue: partials to LDS (16 B-aligned: 52*4 and 832*4 are /16)
    {
        float* rowp = &ldsN[w][c][0];
        *reinterpret_cast<float4v*>(rowp + 4 * g)      = acc0;
        *reinterpret_cast<float4v*>(rowp + 16 + 4 * g) = acc1;
        *reinterpret_cast<float4v*>(rowp + 32 + 4 * g) = acc2;
        if (g == 0) {                               // dens live in ch-row 0
            ldsD[w][c][0] = dac0[0];
            ldsD[w][c][1] = dac1[0];
            ldsD[w][c][2] = dac2[0];
        }
    }
    __syncthreads();

    // ---- block reduction over the 8 chunks + finalize (256 threads)
    if (tid < 256) {
        const int nl = tid >> 4, co = tid & 15;
        float s0 = 0.f, s1 = 0.f, s2 = 0.f, d0 = 0.f, d1 = 0.f, d2 = 0.f;
#pragma unroll
        for (int k = 0; k < NCH; ++k) {
            s0 += ldsN[k][nl][co];
            s1 += ldsN[k][nl][16 + co];
            s2 += ldsN[k][nl][32 + co];
            d0 += ldsD[k][nl][0];
            d1 += ldsD[k][nl][1];
            d2 += ldsD[k][nl][2];
        }
        out[(size_t)(n0 + nl) * 16 + co] = 0.3f * s0 / d0 + 0.3f * s1 / d1 + 0.4f * s2 / d2;
    }
}

// ---------------- fused VALU fallback (workspace too small)
__global__ __launch_bounds__(256) void mgsc_fused(
    const float* __restrict__ x, const float* __restrict__ y,
    const float* __restrict__ yf, float* __restrict__ out)
{
    __shared__ float yS[256 * 3];
    __shared__ float yfS[256 * 16];
    const int tid = threadIdx.x;
    const int n   = blockIdx.x * 256 + tid;
    const float xx = x[3 * n], xy = x[3 * n + 1], xz = x[3 * n + 2];
    float a0[16], a1[16], a2[16];
#pragma unroll
    for (int c = 0; c < 16; ++c) { a0[c] = 0.f; a1[c] = 0.f; a2[c] = 0.f; }
    float den0 = 0.f, den1 = 0.f, den2 = 0.f;
    for (int mt = 0; mt < Mm; mt += 256) {
        const float4* ysrc = reinterpret_cast<const float4*>(y + (size_t)mt * 3);
        if (tid < 192) reinterpret_cast<float4*>(yS)[tid] = ysrc[tid];
        const float4* fsrc = reinterpret_cast<const float4*>(yf + (size_t)mt * 16);
#pragma unroll
        for (int k = 0; k < 4; ++k)
            reinterpret_cast<float4*>(yfS)[tid + 256 * k] = fsrc[tid + 256 * k];
        __syncthreads();
        for (int mm = 0; mm < 256; ++mm) {
            const float dx = xx - yS[3 * mm], dy = xy - yS[3 * mm + 1], dz = xz - yS[3 * mm + 2];
            const float d2 = dx * dx + dy * dy + dz * dz;
            const float e2 = __expf(-12.5f * d2);
            const float t = e2 * e2, e1 = t * t, u = e1 * e1, e0 = u * u;
            den0 += e0; den1 += e1; den2 += e2;
            const float4* fr = reinterpret_cast<const float4*>(yfS + mm * 16);
#pragma unroll
            for (int k = 0; k < 4; ++k) {
                const float4 f = fr[k];
                a0[4*k+0] += e0 * f.x; a0[4*k+1] += e0 * f.y; a0[4*k+2] += e0 * f.z; a0[4*k+3] += e0 * f.w;
                a1[4*k+0] += e1 * f.x; a1[4*k+1] += e1 * f.y; a1[4*k+2] += e1 * f.z; a1[4*k+3] += e1 * f.w;
                a2[4*k+0] += e2 * f.x; a2[4*k+1] += e2 * f.y; a2[4*k+2] += e2 * f.z; a2[4*k+3] += e2 * f.w;
            }
        }
        __syncthreads();
    }
    const float r0 = 0.3f / den0, r1 = 0.3f / den1, r2 = 0.4f / den2;
#pragma unroll
    for (int c = 0; c < 16; ++c)
        out[(size_t)n * 16 + c] = a0[c] * r0 + a1[c] * r1 + a2[c] * r2;
}

extern "C" void kernel_launch(void* const* d_in, const int* in_sizes, int n_in,
                              void* d_out, int out_size, void* d_ws, size_t ws_size,
                              hipStream_t stream) {
    const float* x  = (const float*)d_in[0];
    const float* y  = (const float*)d_in[1];
    const float* yf = (const float*)d_in[2];
    float* out = (float*)d_out;

    const size_t fragyB = (size_t)(Mm / 16) * 512 * sizeof(_Float16); // 512 KB
    const size_t fragfB = (size_t)Mm * 16 * sizeof(_Float16);         // 256 KB
    if (fragyB + fragfB > ws_size) {
        mgsc_fused<<<Nn / 256, 256, 0, stream>>>(x, y, yf, out);
        return;
    }
    _Float16* fragy = (_Float16*)d_ws;
    _Float16* fragf = (_Float16*)((char*)d_ws + fragyB);

    mgsc_prep<<<(Mm * 32) / 256, 256, 0, stream>>>(y, yf, fragy, fragf);
    mgsc_main<<<Nn / 16, 512, 0, stream>>>(x, fragy, fragf, out);
}

// Round 7
// 78.994 us; speedup vs baseline: 1.1160x; 1.0395x over previous
//
#include <hip/hip_runtime.h>

// MultiGaussSpatialConv: B=1, N=M=8192, D=3, C=16, fp32.
// out[n,c] = sum_i w_i * (sum_m e_i(n,m) yf[m,c]) / (sum_m e_i(n,m))
// e_i = exp(-d2/(2 s^2)), 1/(2 s^2) = {200, 50, 12.5} -> e0 = e2^16, e1 = e2^4.
//
// R26 = R25 (82.1 us, absmax 1.953e-3) + predicated A-frag loads. fragy's
// rank-13 A-operand has kk 16..31 structurally zero -> lanes 32..63 of every
// A1a/A1b load fetched zeros (half of fragy's 2 KB/kt). Predicating on
// lane<32 (zero-register substitute) cuts the per-kt L2 stream 3 KB -> 2 KB
// (400 -> 267 MB total) with bit-identical math.
//  - prep: y -> split-fp16 rank-13 arg-A-frags (group-permuted rows so the
//    arg-MFMA D layout feeds the e-MFMA B operand directly, no LDS in loop);
//    yf -> fp16 B-frags (global, L2-resident). (unchanged)
//  - main: one 512-thr block per 16-n tile; 8 waves = 8 m-chunks; verified
//    R20 per-wave body (arg^T 16x16x32 f16 MFMA split-fp16, v_exp_f32,
//    packed fp16 power chain, e-MFMA with yf as A); block-local LDS
//    reduction epilogue (28 KB), no part buffer, no reduce dispatch.

static constexpr int Nn = 8192;
static constexpr int Mm = 8192;
static constexpr int NCH = 8;               // m-chunks = waves per block
static constexpr int MC  = Mm / NCH;        // 1024 m per chunk
static constexpr int NKT = MC / 32;         // kt per wave (32)
static constexpr float KC = 36.0673761f;    // 25 * log2(e)
static constexpr float KD = -18.0336880f;   // -12.5 * log2(e)

typedef _Float16 half8 __attribute__((ext_vector_type(8)));
typedef __fp16  fp16x2 __attribute__((ext_vector_type(2)));
typedef float  float4v __attribute__((ext_vector_type(4)));

#define MFMA_F16 __builtin_amdgcn_mfma_f32_16x16x32_f16
#define EXP2F(v) __builtin_amdgcn_exp2f(v)

// ---------------- prep: y -> split-fp16 arg-A-frags; yf -> fp16 frags
__global__ __launch_bounds__(256) void mgsc_prep(
    const float* __restrict__ y, const float* __restrict__ yf,
    _Float16* __restrict__ fragy, _Float16* __restrict__ fragf)
{
    const int t = blockIdx.x * 256 + threadIdx.x;   // 0 .. Mm*32-1
    const int m = t >> 5, kk = t & 31;
    const float ax = y[3 * m], ay = y[3 * m + 1], az = y[3 * m + 2];
    const float Ycx = KC * ax, Ycy = KC * ay, Ycz = KC * az;
    const _Float16 Yhx = (_Float16)Ycx, Yhy = (_Float16)Ycy, Yhz = (_Float16)Ycz;
    const _Float16 Ylx = (_Float16)(Ycx - (float)Yhx);
    const _Float16 Yly = (_Float16)(Ycy - (float)Yhy);
    const _Float16 Ylz = (_Float16)(Ycz - (float)Yhz);
    const float Wy = KD * __fmaf_rn(ax, ax, __fmaf_rn(ay, ay, az * az));
    const _Float16 Wyh = (_Float16)Wy;
    const _Float16 Wyl = (_Float16)(Wy - (float)Wyh);
    _Float16 v = (_Float16)0.0f;
    switch (kk) {
        case 0: case 6: v = Yhx; break;
        case 1: case 7: v = Yhy; break;
        case 2: case 8: v = Yhz; break;
        case 3: v = Ylx; break;
        case 4: v = Yly; break;
        case 5: v = Ylz; break;
        case 9:  v = Wyh; break;
        case 10: v = Wyl; break;
        case 11: case 12: v = (_Float16)1.0f; break;
        default: break;
    }
    // Group-permuted A-frag placement (R20):
    //   frag pair index = 2*(m>>5) + ((m>>2)&1)
    //   row rho = 4*((m&31)>>3) + (m&3)   (lane-group g = (m&31)>>3)
    //   lane = (kk>>3)*16 + rho, element j = kk&7
    const int fragidx = ((m >> 5) << 1) + ((m >> 2) & 1);
    const int rho = (((m >> 3) & 3) << 2) + (m & 3);
    const int idx = (fragidx << 9) + ((((kk >> 3) << 4) + rho) << 3) + (kk & 7);
    fragy[idx] = v;
    if (t < Mm * 16) {                              // yf frags (same as R13)
        const int m2 = t >> 4, c2 = t & 15;
        const int idx2 = ((m2 >> 5) << 9) + ((((m2 & 31) >> 3) << 4) + c2) * 8 + (m2 & 7);
        fragf[idx2] = (_Float16)yf[t];              // RNE
    }
}

// ---------------- main: grid 512 x 512 thr; wave w = chunk w; one 16-n tile/block
__global__ __launch_bounds__(512, 4) void mgsc_main(
    const float* __restrict__ x, const _Float16* __restrict__ fragy,
    const _Float16* __restrict__ fragf, float* __restrict__ out)
{
    __shared__ float ldsN[NCH][16][52];             // [wave][n_loc][ch 0..47], 52 pad
    __shared__ float ldsD[NCH][16][3];              // dens

    const int tid  = threadIdx.x;
    const int w    = tid >> 6, lane = tid & 63;     // w = wave = m-chunk id
    const int g    = lane >> 4, c = lane & 15;      // c = n_local
    const int n0   = blockIdx.x * 16;
    const int nrow = n0 + c;

    // ---- build x-side B operand for the arg-MFMA (hoisted, per lane)
    const float xx = x[3 * nrow], xy = x[3 * nrow + 1], xz = x[3 * nrow + 2];
    const _Float16 xhx = (_Float16)xx, xhy = (_Float16)xy, xhz = (_Float16)xz;
    const _Float16 xlx = (_Float16)(xx - (float)xhx);
    const _Float16 xly = (_Float16)(xy - (float)xhy);
    const _Float16 xlz = (_Float16)(xz - (float)xhz);
    const float Wx = KD * __fmaf_rn(xx, xx, __fmaf_rn(xy, xy, xz * xz));
    const _Float16 Wxh = (_Float16)Wx;
    const _Float16 Wxl = (_Float16)(Wx - (float)Wxh);
    const _Float16 z16 = (_Float16)0.0f, one16 = (_Float16)1.0f;
    half8 B1;
    if (g == 0)      B1 = half8{xhx, xhy, xhz, xhx, xhy, xhz, xlx, xly};
    else if (g == 1) B1 = half8{xlz, one16, one16, Wxh, Wxl, z16, z16, z16};
    else             B1 = half8{z16, z16, z16, z16, z16, z16, z16, z16};

    float4v acc0 = {0.f, 0.f, 0.f, 0.f}, acc1 = acc0, acc2 = acc0;
    float4v dac0 = acc0, dac1 = acc0, dac2 = acc0;
    const float4v z4 = acc0;
    const half8 zero8 = {z16, z16, z16, z16, z16, z16, z16, z16};

    const _Float16 bv = (c == 0) ? one16 : z16;     // A-ones row 0 -> dens
    half8 boneA = {bv, bv, bv, bv, bv, bv, bv, bv};

    const size_t ybase = (size_t)(w * (MC / 16)) << 9;   // chunk = wave id
    const size_t fbase = (size_t)(w * NKT) << 9;

    for (int ktl = 0; ktl < NKT; ++ktl) {
        // A-frag quads 2,3 (kk 16..31) are structurally zero -> lanes 32..63
        // substitute a zero register instead of fetching zeros (halves fragy
        // L2 traffic; bit-identical MFMA inputs).
        half8 A1a = zero8, A1b = zero8;
        if (lane < 32) {
            A1a = *reinterpret_cast<const half8*>(fragy + ybase + ((size_t)(2 * ktl) << 9) + (lane << 3));
            A1b = *reinterpret_cast<const half8*>(fragy + ybase + ((size_t)(2 * ktl + 1) << 9) + (lane << 3));
        }
        const half8 Af  = *reinterpret_cast<const half8*>(fragf + fbase + ((size_t)ktl << 9) + (lane << 3));

        // arg^T with group-permuted rows: lane (g,c) gets
        //   D1[r] = arg(m = chunk_base + 32*ktl + 8g + r,     n = n0 + c)
        //   D2[r] = arg(m = chunk_base + 32*ktl + 8g + 4 + r, n = n0 + c)
        const float4v D1 = MFMA_F16(A1a, B1, z4, 0, 0, 0);
        const float4v D2 = MFMA_F16(A1b, B1, z4, 0, 0, 0);

        // exp + pack straight into the e-MFMA B-frag (k = 8g+j, col = n)
        union { fp16x2 h2[4]; half8 v; } E2p, E1p, E0p;
        E2p.h2[0] = __builtin_amdgcn_cvt_pkrtz(EXP2F(D1[0]), EXP2F(D1[1]));
        E2p.h2[1] = __builtin_amdgcn_cvt_pkrtz(EXP2F(D1[2]), EXP2F(D1[3]));
        E2p.h2[2] = __builtin_amdgcn_cvt_pkrtz(EXP2F(D2[0]), EXP2F(D2[1]));
        E2p.h2[3] = __builtin_amdgcn_cvt_pkrtz(EXP2F(D2[2]), EXP2F(D2[3]));
#pragma unroll
        for (int jj = 0; jj < 4; ++jj) {
            const fp16x2 s2 = E2p.h2[jj] * E2p.h2[jj];  // v_pk_mul_f16
            E1p.h2[jj] = s2 * s2;                        // e2^4  (sigma 0.1)
            const fp16x2 s1 = E1p.h2[jj] * E1p.h2[jj];
            E0p.h2[jj] = s1 * s1;                        // e2^16 (sigma 0.05)
        }
        // e-MFMA: A = yf^T (row=c, k=m), B = e^T (k=m, col=n)
        acc0 = MFMA_F16(Af, E0p.v, acc0, 0, 0, 0);
        acc1 = MFMA_F16(Af, E1p.v, acc1, 0, 0, 0);
        acc2 = MFMA_F16(Af, E2p.v, acc2, 0, 0, 0);
        dac0 = MFMA_F16(boneA, E0p.v, dac0, 0, 0, 0);
        dac1 = MFMA_F16(boneA, E1p.v, dac1, 0, 0, 0);
        dac2 = MFMA_F16(boneA, E2p.v, dac2, 0, 0, 0);
    }

    // ---- epilogue: partials to LDS (16 B-aligned: 52*4 and 832*4 are /16)
    {
        float* rowp = &ldsN[w][c][0];
        *reinterpret_cast<float4v*>(rowp + 4 * g)      = acc0;
        *reinterpret_cast<float4v*>(rowp + 16 + 4 * g) = acc1;
        *reinterpret_cast<float4v*>(rowp + 32 + 4 * g) = acc2;
        if (g == 0) {                               // dens live in ch-row 0
            ldsD[w][c][0] = dac0[0];
            ldsD[w][c][1] = dac1[0];
            ldsD[w][c][2] = dac2[0];
        }
    }
    __syncthreads();

    // ---- block reduction over the 8 chunks + finalize (256 threads)
    if (tid < 256) {
        const int nl = tid >> 4, co = tid & 15;
        float s0 = 0.f, s1 = 0.f, s2 = 0.f, d0 = 0.f, d1 = 0.f, d2 = 0.f;
#pragma unroll
        for (int k = 0; k < NCH; ++k) {
            s0 += ldsN[k][nl][co];
            s1 += ldsN[k][nl][16 + co];
            s2 += ldsN[k][nl][32 + co];
            d0 += ldsD[k][nl][0];
            d1 += ldsD[k][nl][1];
            d2 += ldsD[k][nl][2];
        }
        out[(size_t)(n0 + nl) * 16 + co] = 0.3f * s0 / d0 + 0.3f * s1 / d1 + 0.4f * s2 / d2;
    }
}

// ---------------- fused VALU fallback (workspace too small)
__global__ __launch_bounds__(256) void mgsc_fused(
    const float* __restrict__ x, const float* __restrict__ y,
    const float* __restrict__ yf, float* __restrict__ out)
{
    __shared__ float yS[256 * 3];
    __shared__ float yfS[256 * 16];
    const int tid = threadIdx.x;
    const int n   = blockIdx.x * 256 + tid;
    const float xx = x[3 * n], xy = x[3 * n + 1], xz = x[3 * n + 2];
    float a0[16], a1[16], a2[16];
#pragma unroll
    for (int c = 0; c < 16; ++c) { a0[c] = 0.f; a1[c] = 0.f; a2[c] = 0.f; }
    float den0 = 0.f, den1 = 0.f, den2 = 0.f;
    for (int mt = 0; mt < Mm; mt += 256) {
        const float4* ysrc = reinterpret_cast<const float4*>(y + (size_t)mt * 3);
        if (tid < 192) reinterpret_cast<float4*>(yS)[tid] = ysrc[tid];
        const float4* fsrc = reinterpret_cast<const float4*>(yf + (size_t)mt * 16);
#pragma unroll
        for (int k = 0; k < 4; ++k)
            reinterpret_cast<float4*>(yfS)[tid + 256 * k] = fsrc[tid + 256 * k];
        __syncthreads();
        for (int mm = 0; mm < 256; ++mm) {
            const float dx = xx - yS[3 * mm], dy = xy - yS[3 * mm + 1], dz = xz - yS[3 * mm + 2];
            const float d2 = dx * dx + dy * dy + dz * dz;
            const float e2 = __expf(-12.5f * d2);
            const float t = e2 * e2, e1 = t * t, u = e1 * e1, e0 = u * u;
            den0 += e0; den1 += e1; den2 += e2;
            const float4* fr = reinterpret_cast<const float4*>(yfS + mm * 16);
#pragma unroll
            for (int k = 0; k < 4; ++k) {
                const float4 f = fr[k];
                a0[4*k+0] += e0 * f.x; a0[4*k+1] += e0 * f.y; a0[4*k+2] += e0 * f.z; a0[4*k+3] += e0 * f.w;
                a1[4*k+0] += e1 * f.x; a1[4*k+1] += e1 * f.y; a1[4*k+2] += e1 * f.z; a1[4*k+3] += e1 * f.w;
                a2[4*k+0] += e2 * f.x; a2[4*k+1] += e2 * f.y; a2[4*k+2] += e2 * f.z; a2[4*k+3] += e2 * f.w;
            }
        }
        __syncthreads();
    }
    const float r0 = 0.3f / den0, r1 = 0.3f / den1, r2 = 0.4f / den2;
#pragma unroll
    for (int c = 0; c < 16; ++c)
        out[(size_t)n * 16 + c] = a0[c] * r0 + a1[c] * r1 + a2[c] * r2;
}

extern "C" void kernel_launch(void* const* d_in, const int* in_sizes, int n_in,
                              void* d_out, int out_size, void* d_ws, size_t ws_size,
                              hipStream_t stream) {
    const float* x  = (const float*)d_in[0];
    const float* y  = (const float*)d_in[1];
    const float* yf = (const float*)d_in[2];
    float* out = (float*)d_out;

    const size_t fragyB = (size_t)(Mm / 16) * 512 * sizeof(_Float16); // 512 KB
    const size_t fragfB = (size_t)Mm * 16 * sizeof(_Float16);         // 256 KB
    if (fragyB + fragfB > ws_size) {
        mgsc_fused<<<Nn / 256, 256, 0, stream>>>(x, y, yf, out);
        return;
    }
    _Float16* fragy = (_Float16*)d_ws;
    _Float16* fragf = (_Float16*)((char*)d_ws + fragyB);

    mgsc_prep<<<(Mm * 32) / 256, 256, 0, stream>>>(y, yf, fragy, fragf);
    mgsc_main<<<Nn / 16, 512, 0, stream>>>(x, fragy, fragf, out);
}